// Round 10
// baseline (444.539 us; speedup 1.0000x reference)
//
#include <hip/hip_runtime.h>
#include <hip/hip_bf16.h>

// FraudSNN fused kernel: GEMM (bf16 MFMA) + LIF recurrence, T=10, F=256, H=512.
// R10: allocator model from R3-R9: 512-thr blocks -> 128 VGPR budget, 1024-thr -> 64,
// hints don't move it. So: 512 threads, 32 rows/block, mem1-in-LDS (74 KB total) ->
// 2 blocks/CU (cross-block latency hiding, R7's missing ingredient), live regs ~85
// (no w1r persistence) -> spill-free inside the 128 budget. Keep T14 x-prefetch +
// redundant LIF2 from R8.

typedef short short8 __attribute__((ext_vector_type(8)));
typedef float f32x4 __attribute__((ext_vector_type(4)));

__device__ __forceinline__ unsigned short bfbits(float f) {
  union { __hip_bfloat16 h; unsigned short u; } c;
  c.h = __float2bfloat16(f);   // hardware RNE
  return c.u;
}

__device__ __forceinline__ unsigned int bfpack(float a, float b) {
  return (unsigned int)bfbits(a) | ((unsigned int)bfbits(b) << 16);
}

__device__ __forceinline__ float fast_sigmoid(float z) {
  float e = __expf(-z);
  return __builtin_amdgcn_rcpf(1.0f + e);
}

__global__ void w1_to_bf16(const float* __restrict__ w1, unsigned short* __restrict__ o) {
  int i = blockIdx.x * 256 + threadIdx.x;      // 32768 float4s = 131072 floats
  float4 v = reinterpret_cast<const float4*>(w1)[i];
  reinterpret_cast<uint2*>(o)[i] = make_uint2(bfpack(v.x, v.y), bfpack(v.z, v.w));
}

// 512 threads = 8 waves. Block: 32 batch rows; wave w owns 32 rows x h in [w*64, w*64+64).
template <bool USE_WS>
__global__
__attribute__((amdgpu_flat_work_group_size(512, 512), amdgpu_waves_per_eu(4, 4)))
void snn_main(const float* __restrict__ x,
              const unsigned short* __restrict__ w1bf,  // bf16 W1 (if USE_WS)
              const float* __restrict__ w1f,            // fp32 W1 (fallback)
              const float* __restrict__ b1,
              const float* __restrict__ w2,
              const float* __restrict__ b2,
              float* __restrict__ out)
{
  // mem1 state: plane p = rt*4+ct, per-thread f32x4 slot -> 8*512*16 B = 64 KB
  __shared__ __align__(16) float mem_lds[8][512][4];
  __shared__ __align__(16) unsigned short xt[32][132];  // one 128-col k-half, bf16 (8.4 KB)
  __shared__ float red[32][9];                          // [row][wave] partial cur2 (1.2 KB)

  const int tid  = threadIdx.x;
  const int lane = tid & 63;
  const int wave = tid >> 6;          // 0..7
  const int l15  = lane & 15;
  const int lq   = lane >> 4;         // 0..3
  const long b0  = (long)blockIdx.x * 32;
  const int h0   = wave * 64;         // 64 h-cols per wave (4 col-tiles of 16)

  float w2l[4], b1l[4];
#pragma unroll
  for (int ct = 0; ct < 4; ++ct) {
    int h = h0 + ct * 16 + l15;
    w2l[ct] = w2[h];
    b1l[ct] = b1[h];
  }
  const float bias2 = b2[0];

  // zero-init mem1 planes (own slot each)
#pragma unroll
  for (int p = 0; p < 8; ++p) {
    f32x4 z = {0.f, 0.f, 0.f, 0.f};
    *reinterpret_cast<f32x4*>(&mem_lds[p][tid][0]) = z;
  }

  float mem2 = 0.f, spksum = 0.f;   // per-thread redundant (16 replicas per row)

  // staging geometry: thread stages rows r0 and r0+16, float4 index c4 in a 128-col half
  const int r0 = tid >> 5;            // 0..15
  const int c4 = tid & 31;            // 0..31
  const float* xp0 = x + (b0 + r0) * 2560 + c4 * 4;        // row r0, t=0, k=0
  const float* xp1 = x + (b0 + r0 + 16) * 2560 + c4 * 4;   // row r0+16

  // prologue: prefetch half0 of t=0
  float4 pf0 = *reinterpret_cast<const float4*>(xp0);
  float4 pf1 = *reinterpret_cast<const float4*>(xp1);

#pragma unroll 1
  for (int t = 0; t < 10; ++t) {
    // ---- A: write prefetched half0 -> xt; issue half1 loads ----
    *reinterpret_cast<uint2*>(&xt[r0][c4 * 4]) =
        make_uint2(bfpack(pf0.x, pf0.y), bfpack(pf0.z, pf0.w));
    *reinterpret_cast<uint2*>(&xt[r0 + 16][c4 * 4]) =
        make_uint2(bfpack(pf1.x, pf1.y), bfpack(pf1.z, pf1.w));
    pf0 = *reinterpret_cast<const float4*>(xp0 + t * 256 + 128);
    pf1 = *reinterpret_cast<const float4*>(xp1 + t * 256 + 128);
    __syncthreads();

    f32x4 acc[2][4];
#pragma unroll
    for (int rt = 0; rt < 2; ++rt)
#pragma unroll
      for (int ct = 0; ct < 4; ++ct) {
        f32x4 c = { b1l[ct], b1l[ct], b1l[ct], b1l[ct] };
        acc[rt][ct] = c;
      }

    // ---- B: MFMA k-half 0 (kk 0..3), W1 from L2 ----
#pragma unroll
    for (int kkL = 0; kkL < 4; ++kkL) {
      short8 a[2], bfr[4];
#pragma unroll
      for (int rt = 0; rt < 2; ++rt)
        a[rt] = *reinterpret_cast<const short8*>(&xt[rt * 16 + l15][kkL * 32 + lq * 8]);
#pragma unroll
      for (int ct = 0; ct < 4; ++ct) {
        if constexpr (USE_WS) {
          bfr[ct] = *reinterpret_cast<const short8*>(
              w1bf + (h0 + ct * 16 + l15) * 256 + kkL * 32 + lq * 8);
        } else {
          const float* wp = w1f + (h0 + ct * 16 + l15) * 256 + kkL * 32 + lq * 8;
          const float4 v0 = *reinterpret_cast<const float4*>(wp);
          const float4 v1 = *reinterpret_cast<const float4*>(wp + 4);
          union { unsigned int u[4]; short8 s; } cv;
          cv.u[0] = bfpack(v0.x, v0.y);
          cv.u[1] = bfpack(v0.z, v0.w);
          cv.u[2] = bfpack(v1.x, v1.y);
          cv.u[3] = bfpack(v1.z, v1.w);
          bfr[ct] = cv.s;
        }
      }
#pragma unroll
      for (int rt = 0; rt < 2; ++rt)
#pragma unroll
        for (int ct = 0; ct < 4; ++ct)
          acc[rt][ct] = __builtin_amdgcn_mfma_f32_16x16x32_bf16(a[rt], bfr[ct], acc[rt][ct], 0, 0, 0);
    }
    __syncthreads();

    // ---- D: write half1 -> xt; issue half0 loads of t+1 ----
    *reinterpret_cast<uint2*>(&xt[r0][c4 * 4]) =
        make_uint2(bfpack(pf0.x, pf0.y), bfpack(pf0.z, pf0.w));
    *reinterpret_cast<uint2*>(&xt[r0 + 16][c4 * 4]) =
        make_uint2(bfpack(pf1.x, pf1.y), bfpack(pf1.z, pf1.w));
    const int tn = (t < 9) ? t + 1 : 9;   // t=9: harmless re-read, keeps code branch-free
    pf0 = *reinterpret_cast<const float4*>(xp0 + tn * 256);
    pf1 = *reinterpret_cast<const float4*>(xp1 + tn * 256);
    __syncthreads();

    // ---- E: MFMA k-half 1 (kk 4..7), W1 from L2 ----
#pragma unroll
    for (int kkL = 0; kkL < 4; ++kkL) {
      const int kkg = 4 + kkL;
      short8 a[2], bfr[4];
#pragma unroll
      for (int rt = 0; rt < 2; ++rt)
        a[rt] = *reinterpret_cast<const short8*>(&xt[rt * 16 + l15][kkL * 32 + lq * 8]);
#pragma unroll
      for (int ct = 0; ct < 4; ++ct) {
        if constexpr (USE_WS) {
          bfr[ct] = *reinterpret_cast<const short8*>(
              w1bf + (h0 + ct * 16 + l15) * 256 + kkg * 32 + lq * 8);
        } else {
          const float* wp = w1f + (h0 + ct * 16 + l15) * 256 + kkg * 32 + lq * 8;
          const float4 v0 = *reinterpret_cast<const float4*>(wp);
          const float4 v1 = *reinterpret_cast<const float4*>(wp + 4);
          union { unsigned int u[4]; short8 s; } cv;
          cv.u[0] = bfpack(v0.x, v0.y);
          cv.u[1] = bfpack(v0.z, v0.w);
          cv.u[2] = bfpack(v1.x, v1.y);
          cv.u[3] = bfpack(v1.z, v1.w);
          bfr[ct] = cv.s;
        }
      }
#pragma unroll
      for (int rt = 0; rt < 2; ++rt)
#pragma unroll
        for (int ct = 0; ct < 4; ++ct)
          acc[rt][ct] = __builtin_amdgcn_mfma_f32_16x16x32_bf16(a[rt], bfr[ct], acc[rt][ct], 0, 0, 0);
    }

    // ---- F: LIF1 (mem1 in LDS) + partial W2 dot; reduce per rt ----
#pragma unroll
    for (int rt = 0; rt < 2; ++rt) {
      float pr[4] = {0.f, 0.f, 0.f, 0.f};
#pragma unroll
      for (int ct = 0; ct < 4; ++ct) {
        f32x4* slot = reinterpret_cast<f32x4*>(&mem_lds[rt * 4 + ct][tid][0]);
        f32x4 mv = *slot;
#pragma unroll
        for (int e = 0; e < 4; ++e) {
          float m   = fmaf(mv[e], 0.9f, acc[rt][ct][e]);   // beta*mem + cur1
          float spk = fast_sigmoid(fmaf(m, 10.f, -10.f));  // sigmoid(10*(m-1))
          mv[e] = m - spk;
          pr[e] = fmaf(spk, w2l[ct], pr[e]);
        }
        *slot = mv;
      }
#pragma unroll
      for (int e = 0; e < 4; ++e) {
        float v = pr[e];
        v += __shfl_xor(v, 1);
        v += __shfl_xor(v, 2);
        v += __shfl_xor(v, 4);
        v += __shfl_xor(v, 8);
        if (l15 == 0) red[rt * 16 + lq * 4 + e][wave] = v;
      }
    }
    __syncthreads();

    // ---- H: LIF2, redundant on all threads (row = lane&31); red next rewritten in
    //      F(t+1), which is behind the A and D barriers of t+1 ----
    {
      float c2 = bias2;
#pragma unroll
      for (int w = 0; w < 8; ++w) c2 += red[lane & 31][w];
      float m   = fmaf(mem2, 0.9f, c2);
      float spk = fast_sigmoid(fmaf(m, 10.f, -10.f));
      mem2   = m - spk;
      spksum += spk;
    }
  }

  if (tid < 32) {
    float y = fast_sigmoid(spksum * 0.1f);
    out[b0 + tid] = y;                      // FLOAT32 output
  }
}

extern "C" void kernel_launch(void* const* d_in, const int* in_sizes, int n_in,
                              void* d_out, int out_size, void* d_ws, size_t ws_size,
                              hipStream_t stream) {
  const float* x  = (const float*)d_in[0];
  const float* W1 = (const float*)d_in[1];
  const float* b1 = (const float*)d_in[2];
  const float* W2 = (const float*)d_in[3];
  const float* b2 = (const float*)d_in[4];
  float* out = (float*)d_out;
  (void)in_sizes; (void)n_in;

  const int grid = out_size / 32;   // out_size == B == 32768 -> 1024 blocks

  if (ws_size >= 512 * 256 * sizeof(unsigned short)) {
    unsigned short* w1bf = (unsigned short*)d_ws;   // 256 KB
    w1_to_bf16<<<128, 256, 0, stream>>>(W1, w1bf);
    snn_main<true><<<grid, 512, 0, stream>>>(x, w1bf, W1, b1, W2, b2, out);
  } else {
    snn_main<false><<<grid, 512, 0, stream>>>(x, nullptr, W1, b1, W2, b2, out);
  }
}